// Round 6
// baseline (421.481 us; speedup 1.0000x reference)
//
#include <hip/hip_runtime.h>
#include <cstddef>

#define WIN 11
#define HALO 10
#define NCH 10

typedef float v2f __attribute__((ext_vector_type(2)));

// Normalized 1D Gaussian, sigma=1.5 (constexpr: unrolled taps fold to immediates)
constexpr float Gc[WIN] = {
    0.00102838f, 0.00759876f, 0.03600077f, 0.10936069f, 0.21300554f,
    0.26601173f, 0.21300554f, 0.10936069f, 0.03600077f, 0.00759876f,
    0.00102838f};

constexpr int TX = 32;
constexpr int TY = 24;              // 24-tall tiles: LDS 22.4 KB -> 7 blocks/CU
constexpr int IN_H = TY + HALO;     // 34 h-rows per tile
constexpr int HPITCH = 33;          // write bank spread; stage-2 reads clean
constexpr int HSZ = IN_H * HPITCH;  // 1122

// Per-level pair-tile counts (64-wide pair x 24-tall):
// lvl0: 16*ceil(1014/24)=16*43=688, lvl1: 8*21=168, lvl2: 4*11=44,
// lvl3: 2*5=10, lvl4: 1*3=3  -> 913 total
constexpr int B0 = 688, B1 = 856, B2 = 900, B3 = 910, BT = 913;

struct Ptrs {
    const float* p[5];
    const float* t[5];
};

// ---- One-shot pyramid: 64x64 level-0 tile -> levels 1..4, plus acc zeroing ----
__global__ __launch_bounds__(256) void pool_all(
    const float* __restrict__ P0, const float* __restrict__ T0,
    float* __restrict__ p1, float* __restrict__ t1,
    float* __restrict__ p2, float* __restrict__ t2,
    float* __restrict__ p3, float* __restrict__ t3,
    float* __restrict__ p4, float* __restrict__ t4,
    float* __restrict__ acc) {
    __shared__ float sp2[256], st2[256], sp3[64], st3[64];
    const int tid = threadIdx.x;
    if (blockIdx.x == 0 && tid < 128) acc[tid] = 0.f;

    const int b = blockIdx.x;  // 2560 = 10ch x 16 x 16
    const int bx = b & 15, by = (b >> 4) & 15, ch = b >> 8;
    const int tx = tid & 15, ty = tid >> 4;

    const size_t rbase =
        ((size_t)ch * 1024 + by * 64 + ty * 4) * 1024 + bx * 64 + tx * 4;
    float4 pr[4], tr[4];
#pragma unroll
    for (int r2 = 0; r2 < 4; ++r2) {
        pr[r2] = *(const float4*)(P0 + rbase + (size_t)r2 * 1024);
        tr[r2] = *(const float4*)(T0 + rbase + (size_t)r2 * 1024);
    }
    float p1a = 0.25f * ((pr[0].x + pr[0].y) + (pr[1].x + pr[1].y));
    float p1b = 0.25f * ((pr[0].z + pr[0].w) + (pr[1].z + pr[1].w));
    float p1c = 0.25f * ((pr[2].x + pr[2].y) + (pr[3].x + pr[3].y));
    float p1d = 0.25f * ((pr[2].z + pr[2].w) + (pr[3].z + pr[3].w));
    float t1a = 0.25f * ((tr[0].x + tr[0].y) + (tr[1].x + tr[1].y));
    float t1b = 0.25f * ((tr[0].z + tr[0].w) + (tr[1].z + tr[1].w));
    float t1c = 0.25f * ((tr[2].x + tr[2].y) + (tr[3].x + tr[3].y));
    float t1d = 0.25f * ((tr[2].z + tr[2].w) + (tr[3].z + tr[3].w));
    size_t o1 = ((size_t)ch * 512 + by * 32 + ty * 2) * 512 + bx * 32 + tx * 2;
    *(float2*)(p1 + o1) = make_float2(p1a, p1b);
    *(float2*)(p1 + o1 + 512) = make_float2(p1c, p1d);
    *(float2*)(t1 + o1) = make_float2(t1a, t1b);
    *(float2*)(t1 + o1 + 512) = make_float2(t1c, t1d);
    float p2v = 0.25f * ((p1a + p1b) + (p1c + p1d));
    float t2v = 0.25f * ((t1a + t1b) + (t1c + t1d));
    size_t o2 = ((size_t)ch * 256 + by * 16 + ty) * 256 + bx * 16 + tx;
    p2[o2] = p2v;
    t2[o2] = t2v;
    sp2[tid] = p2v;
    st2[tid] = t2v;
    __syncthreads();
    if (tid < 64) {
        int x3 = tid & 7, y3 = tid >> 3;
        int i0 = (2 * y3) * 16 + 2 * x3;
        float p3v = 0.25f * ((sp2[i0] + sp2[i0 + 1]) + (sp2[i0 + 16] + sp2[i0 + 17]));
        float t3v = 0.25f * ((st2[i0] + st2[i0 + 1]) + (st2[i0 + 16] + st2[i0 + 17]));
        size_t o3 = ((size_t)ch * 128 + by * 8 + y3) * 128 + bx * 8 + x3;
        p3[o3] = p3v;
        t3[o3] = t3v;
        sp3[tid] = p3v;
        st3[tid] = t3v;
    }
    __syncthreads();
    if (tid < 16) {
        int x4 = tid & 3, y4 = tid >> 2;
        int i0 = (2 * y4) * 8 + 2 * x4;
        float p4v = 0.25f * ((sp3[i0] + sp3[i0 + 1]) + (sp3[i0 + 8] + sp3[i0 + 9]));
        float t4v = 0.25f * ((st3[i0] + st3[i0 + 1]) + (st3[i0 + 8] + st3[i0 + 9]));
        size_t o4 = ((size_t)ch * 64 + by * 4 + y4) * 64 + bx * 4 + x4;
        p4[o4] = p4v;
        t4[o4] = t4v;
    }
}

// All 5 levels, two adjacent 32-wide x-tiles per block, 24-tall, packed fp32.
// 7 blocks/CU (28 waves) for latency hiding. blockIdx.y = channel.
__global__ __launch_bounds__(256, 7) void ssim_all(Ptrs ptrs,
                                                   float* __restrict__ acc) {
    __shared__ v2f h01[HSZ];   // (conv(p), conv(t))       8976 B
    __shared__ v2f h23[HSZ];   // (conv(p^2), conv(t^2))   8976 B
    __shared__ float h4s[HSZ]; // conv(p*t)                 4488 B
    __shared__ float red[8];

    const int bxi = blockIdx.x;
    int lvl, base;
    if (bxi < B0)      { lvl = 0; base = 0; }
    else if (bxi < B1) { lvl = 1; base = B0; }
    else if (bxi < B2) { lvl = 2; base = B1; }
    else if (bxi < B3) { lvl = 3; base = B2; }
    else               { lvl = 4; base = B3; }
    const int local = bxi - base;
    const int pw_ = 16 >> lvl;              // pairs per row (pow2)
    const int pxb = local & (pw_ - 1);
    const int tyb = local >> (4 - lvl);
    const int H = 1024 >> lvl;
    const int Hout = H - HALO;
    const int oxp = pxb * 64;
    const int oy0 = tyb * TY;
    const int c = blockIdx.y;
    const float* Pc = ptrs.p[lvl] + (size_t)c * H * H;
    const float* Tc = ptrs.t[lvl] + (size_t)c * H * H;
    const int tid = threadIdx.x;
    const int r = tid / 6;        // h-row 0..33 (threads 204..255 idle in stage 1)
    const int seg = tid - r * 6;
    const int x0s = seg * 6;
    const int gy = oy0 + r;

    float cs_sum = 0.f, sim_sum = 0.f;
#pragma unroll
    for (int s = 0; s < 2; ++s) {
        if (s == 1) __syncthreads();  // hbuf reuse guard

        // ---- Stage 1: horizontal conv from global, packed accumulators ----
        if (r < IN_H) {
            const int gxb = oxp + s * TX + x0s;
            const float* Pr = Pc + (size_t)gy * H + gxb;
            const float* Tr = Tc + (size_t)gy * H + gxb;
            v2f win[16];  // (p, t)
            if (gy < H && gxb + 16 <= H) {  // fast path
#pragma unroll
                for (int j = 0; j < 8; ++j) {
                    float2 pv = *(const float2*)(Pr + 2 * j);
                    float2 tv = *(const float2*)(Tr + 2 * j);
                    win[2 * j] = (v2f){pv.x, tv.x};
                    win[2 * j + 1] = (v2f){pv.y, tv.y};
                }
            } else {
#pragma unroll
                for (int j = 0; j < 16; ++j) {
                    bool ok = (gy < H) && (gxb + j < H);
                    win[j] = (v2f){ok ? Pr[j] : 0.f, ok ? Tr[j] : 0.f};
                }
            }
            v2f a01[6] = {}, a23[6] = {};
            float a4[6] = {};
#pragma unroll
            for (int xi = 0; xi < 16; ++xi) {
                v2f x01 = win[xi];
                v2f x23 = x01 * x01;      // v_pk_mul_f32
                float x4 = x01.x * x01.y;
#pragma unroll
                for (int o = 0; o < 6; ++o) {
                    int k = xi - o;
                    if (k >= 0 && k <= 10) {
                        float g = Gc[k];
                        a01[o] = a01[o] + g * x01;  // v_pk_fma_f32
                        a23[o] = a23[o] + g * x23;
                        a4[o] = fmaf(g, x4, a4[o]);
                    }
                }
            }
#pragma unroll
            for (int o = 0; o < 6; ++o) {
                int x = x0s + o;
                if (x < TX) {
                    int idx = r * HPITCH + x;
                    h01[idx] = a01[o];  // ds_write_b64
                    h23[idx] = a23[o];
                    h4s[idx] = a4[o];
                }
            }
        }
        __syncthreads();

        // ---- Stage 2: vertical conv + SSIM, packed, 3 outputs/thread ----
        {
            const int txl = tid & 31;
            const int y0 = (tid >> 5) * 3;  // 8 thread-rows x 3 = 24 outputs
            v2f m12[3] = {}, q12v[3] = {};
            float sA[3] = {};
#pragma unroll
            for (int yr = 0; yr < 13; ++yr) {  // 3 + 10 streamed rows
                int row = (y0 + yr) * HPITCH + txl;
                v2f v01 = h01[row];   // ds_read_b64
                v2f v23 = h23[row];
                float v4 = h4s[row];  // ds_read_b32
#pragma unroll
                for (int o = 0; o < 3; ++o) {
                    int k = yr - o;
                    if (k >= 0 && k <= 10) {
                        float gw = Gc[k];
                        m12[o] = m12[o] + gw * v01;
                        q12v[o] = q12v[o] + gw * v23;
                        sA[o] = fmaf(gw, v4, sA[o]);
                    }
                }
            }
            const float C1c = 1.0e-4f, C2c = 9.0e-4f;
            const int ox = oxp + s * TX + txl;
#pragma unroll
            for (int o = 0; o < 3; ++o) {
                if (ox < Hout && oy0 + y0 + o < Hout) {
                    float mu1 = m12[o].x, mu2 = m12[o].y;
                    float mu1s = mu1 * mu1, mu2s = mu2 * mu2, mu12 = mu1 * mu2;
                    float sig1 = q12v[o].x - mu1s;
                    float sig2 = q12v[o].y - mu2s;
                    float sig12 = sA[o] - mu12;
                    float v1 = 2.f * sig12 + C2c;
                    float v2 = sig1 + sig2 + C2c;
                    float den2 = mu1s + mu2s + C1c;
                    float num2 = 2.f * mu12 + C1c;
                    float inv = 1.f / (v2 * den2);  // one divide for both terms
                    cs_sum = fmaf(v1 * den2, inv, cs_sum);
                    sim_sum = fmaf(num2 * v1, inv, sim_sum);
                }
            }
        }
    }

    // ---- Block reduction (once per pair) ----
#pragma unroll
    for (int off = 32; off > 0; off >>= 1) {
        cs_sum += __shfl_down(cs_sum, off, 64);
        sim_sum += __shfl_down(sim_sum, off, 64);
    }
    int wave = tid >> 6;
    if ((tid & 63) == 0) {
        red[wave * 2 + 0] = sim_sum;
        red[wave * 2 + 1] = cs_sum;
    }
    __syncthreads();
    if (tid == 0) {
        float s = red[0] + red[2] + red[4] + red[6];
        float cc = red[1] + red[3] + red[5] + red[7];
        atomicAdd(&acc[(lvl * NCH + c) * 2 + 0], s);
        atomicAdd(&acc[(lvl * NCH + c) * 2 + 1], cc);
    }
}

__global__ void finalize_k(const float* __restrict__ acc, float* __restrict__ out) {
    if (threadIdx.x != 0) return;
    const double w[5] = {0.0448, 0.2856, 0.3001, 0.2363, 0.1333};
    const double counts[5] = {1014.0 * 1014.0, 502.0 * 502.0, 246.0 * 246.0,
                              118.0 * 118.0, 54.0 * 54.0};
    double total = 0.0;
    for (int c = 0; c < NCH; ++c) {
        double pc = 1.0;
        for (int l = 0; l < 4; ++l) {
            double mcs = (double)acc[(l * NCH + c) * 2 + 1] / counts[l];
            pc *= pow(mcs, w[l]);
        }
        double ms4 = (double)acc[(4 * NCH + c) * 2 + 0] / counts[4];
        double p2 = pow(ms4, w[4]);
        pc *= (p2 * p2) * (p2 * p2);  // pow2[-1] appears in all 4 product terms
        total += pc;
    }
    *out = (float)(1.0 - total);
}

extern "C" void kernel_launch(void* const* d_in, const int* in_sizes, int n_in,
                              void* d_out, int out_size, void* d_ws, size_t ws_size,
                              hipStream_t stream) {
    const float* P0 = (const float*)d_in[0];
    const float* T0 = (const float*)d_in[1];
    float* out = (float*)d_out;
    float* acc = (float*)d_ws;  // 100 used, 128 reserved

    const size_t n1 = (size_t)NCH * 512 * 512;
    const size_t n2 = (size_t)NCH * 256 * 256;
    const size_t n3 = (size_t)NCH * 128 * 128;
    const size_t n4 = (size_t)NCH * 64 * 64;
    float* p1 = acc + 128;
    float* t1 = p1 + n1;
    float* p2 = t1 + n1;
    float* t2 = p2 + n2;
    float* p3 = t2 + n2;
    float* t3 = p3 + n3;
    float* p4 = t3 + n3;
    float* t4 = p4 + n4;

    pool_all<<<2560, 256, 0, stream>>>(P0, T0, p1, t1, p2, t2, p3, t3, p4, t4, acc);

    Ptrs ptrs;
    ptrs.p[0] = P0; ptrs.t[0] = T0;
    ptrs.p[1] = p1; ptrs.t[1] = t1;
    ptrs.p[2] = p2; ptrs.t[2] = t2;
    ptrs.p[3] = p3; ptrs.t[3] = t3;
    ptrs.p[4] = p4; ptrs.t[4] = t4;

    ssim_all<<<dim3(BT, NCH, 1), 256, 0, stream>>>(ptrs, acc);

    finalize_k<<<1, 64, 0, stream>>>(acc, out);
}

// Round 7
// 305.898 us; speedup vs baseline: 1.3779x; 1.3779x over previous
//
#include <hip/hip_runtime.h>
#include <cstddef>

#define WIN 11
#define HALO 10
#define NCH 10

typedef float v2f __attribute__((ext_vector_type(2)));

// Normalized 1D Gaussian, sigma=1.5 (constexpr: unrolled taps fold to immediates)
constexpr float Gc[WIN] = {
    0.00102838f, 0.00759876f, 0.03600077f, 0.10936069f, 0.21300554f,
    0.26601173f, 0.21300554f, 0.10936069f, 0.03600077f, 0.00759876f,
    0.00102838f};

constexpr int TX = 32;
constexpr int TY = 24;              // 24-tall tiles: LDS 22.4 KB -> 7 blocks/CU
constexpr int IN_H = TY + HALO;     // 34 h-rows per tile
constexpr int HPITCH = 33;          // write bank spread; stage-2 reads clean
constexpr int HSZ = IN_H * HPITCH;  // 1122

// Per-level pair-tile counts (64-wide pair x 24-tall):
// lvl0: 16*ceil(1014/24)=16*43=688, lvl1: 8*21=168, lvl2: 4*11=44,
// lvl3: 2*5=10, lvl4: 1*3=3  -> 913 total
constexpr int B0 = 688, B1 = 856, B2 = 900, B3 = 910, BT = 913;

struct Ptrs {
    const float* p[5];
    const float* t[5];
};

// ---- One-shot pyramid: 64x64 level-0 tile -> levels 1..4, plus acc zeroing ----
__global__ __launch_bounds__(256) void pool_all(
    const float* __restrict__ P0, const float* __restrict__ T0,
    float* __restrict__ p1, float* __restrict__ t1,
    float* __restrict__ p2, float* __restrict__ t2,
    float* __restrict__ p3, float* __restrict__ t3,
    float* __restrict__ p4, float* __restrict__ t4,
    float* __restrict__ acc) {
    __shared__ float sp2[256], st2[256], sp3[64], st3[64];
    const int tid = threadIdx.x;
    if (blockIdx.x == 0 && tid < 128) acc[tid] = 0.f;

    const int b = blockIdx.x;  // 2560 = 10ch x 16 x 16
    const int bx = b & 15, by = (b >> 4) & 15, ch = b >> 8;
    const int tx = tid & 15, ty = tid >> 4;

    const size_t rbase =
        ((size_t)ch * 1024 + by * 64 + ty * 4) * 1024 + bx * 64 + tx * 4;
    float4 pr[4], tr[4];
#pragma unroll
    for (int r2 = 0; r2 < 4; ++r2) {
        pr[r2] = *(const float4*)(P0 + rbase + (size_t)r2 * 1024);
        tr[r2] = *(const float4*)(T0 + rbase + (size_t)r2 * 1024);
    }
    float p1a = 0.25f * ((pr[0].x + pr[0].y) + (pr[1].x + pr[1].y));
    float p1b = 0.25f * ((pr[0].z + pr[0].w) + (pr[1].z + pr[1].w));
    float p1c = 0.25f * ((pr[2].x + pr[2].y) + (pr[3].x + pr[3].y));
    float p1d = 0.25f * ((pr[2].z + pr[2].w) + (pr[3].z + pr[3].w));
    float t1a = 0.25f * ((tr[0].x + tr[0].y) + (tr[1].x + tr[1].y));
    float t1b = 0.25f * ((tr[0].z + tr[0].w) + (tr[1].z + tr[1].w));
    float t1c = 0.25f * ((tr[2].x + tr[2].y) + (tr[3].x + tr[3].y));
    float t1d = 0.25f * ((tr[2].z + tr[2].w) + (tr[3].z + tr[3].w));
    size_t o1 = ((size_t)ch * 512 + by * 32 + ty * 2) * 512 + bx * 32 + tx * 2;
    *(float2*)(p1 + o1) = make_float2(p1a, p1b);
    *(float2*)(p1 + o1 + 512) = make_float2(p1c, p1d);
    *(float2*)(t1 + o1) = make_float2(t1a, t1b);
    *(float2*)(t1 + o1 + 512) = make_float2(t1c, t1d);
    float p2v = 0.25f * ((p1a + p1b) + (p1c + p1d));
    float t2v = 0.25f * ((t1a + t1b) + (t1c + t1d));
    size_t o2 = ((size_t)ch * 256 + by * 16 + ty) * 256 + bx * 16 + tx;
    p2[o2] = p2v;
    t2[o2] = t2v;
    sp2[tid] = p2v;
    st2[tid] = t2v;
    __syncthreads();
    if (tid < 64) {
        int x3 = tid & 7, y3 = tid >> 3;
        int i0 = (2 * y3) * 16 + 2 * x3;
        float p3v = 0.25f * ((sp2[i0] + sp2[i0 + 1]) + (sp2[i0 + 16] + sp2[i0 + 17]));
        float t3v = 0.25f * ((st2[i0] + st2[i0 + 1]) + (st2[i0 + 16] + st2[i0 + 17]));
        size_t o3 = ((size_t)ch * 128 + by * 8 + y3) * 128 + bx * 8 + x3;
        p3[o3] = p3v;
        t3[o3] = t3v;
        sp3[tid] = p3v;
        st3[tid] = t3v;
    }
    __syncthreads();
    if (tid < 16) {
        int x4 = tid & 3, y4 = tid >> 2;
        int i0 = (2 * y4) * 8 + 2 * x4;
        float p4v = 0.25f * ((sp3[i0] + sp3[i0 + 1]) + (sp3[i0 + 8] + sp3[i0 + 9]));
        float t4v = 0.25f * ((st3[i0] + st3[i0 + 1]) + (st3[i0 + 8] + st3[i0 + 9]));
        size_t o4 = ((size_t)ch * 64 + by * 4 + y4) * 64 + bx * 4 + x4;
        p4[o4] = p4v;
        t4[o4] = t4v;
    }
}

// All 5 levels, two adjacent 32-wide x-tiles per block, 24-tall, packed fp32.
// LDS 22.5 KB -> 7 blocks/CU; NO aggressive VGPR cap (R6's (256,7) forced
// ~930 MB of scratch spill traffic — WRITE_SIZE 505 MB — and regressed 2x).
__global__ __launch_bounds__(256, 4) void ssim_all(Ptrs ptrs,
                                                   float* __restrict__ acc) {
    __shared__ v2f h01[HSZ];   // (conv(p), conv(t))       8976 B
    __shared__ v2f h23[HSZ];   // (conv(p^2), conv(t^2))   8976 B
    __shared__ float h4s[HSZ]; // conv(p*t)                 4488 B
    __shared__ float red[8];

    const int bxi = blockIdx.x;
    int lvl, base;
    if (bxi < B0)      { lvl = 0; base = 0; }
    else if (bxi < B1) { lvl = 1; base = B0; }
    else if (bxi < B2) { lvl = 2; base = B1; }
    else if (bxi < B3) { lvl = 3; base = B2; }
    else               { lvl = 4; base = B3; }
    const int local = bxi - base;
    const int pw_ = 16 >> lvl;              // pairs per row (pow2)
    const int pxb = local & (pw_ - 1);
    const int tyb = local >> (4 - lvl);
    const int H = 1024 >> lvl;
    const int Hout = H - HALO;
    const int oxp = pxb * 64;
    const int oy0 = tyb * TY;
    const int c = blockIdx.y;
    const float* Pc = ptrs.p[lvl] + (size_t)c * H * H;
    const float* Tc = ptrs.t[lvl] + (size_t)c * H * H;
    const int tid = threadIdx.x;
    const int r = tid / 6;        // h-row 0..33 (threads 204..255 idle in stage 1)
    const int seg = tid - r * 6;
    const int x0s = seg * 6;
    const int gy = oy0 + r;

    float cs_sum = 0.f, sim_sum = 0.f;
#pragma unroll
    for (int s = 0; s < 2; ++s) {
        if (s == 1) __syncthreads();  // hbuf reuse guard

        // ---- Stage 1: horizontal conv from global, packed accumulators ----
        if (r < IN_H) {
            const int gxb = oxp + s * TX + x0s;
            const float* Pr = Pc + (size_t)gy * H + gxb;
            const float* Tr = Tc + (size_t)gy * H + gxb;
            v2f win[16];  // (p, t)
            if (gy < H && gxb + 16 <= H) {  // fast path
#pragma unroll
                for (int j = 0; j < 8; ++j) {
                    float2 pv = *(const float2*)(Pr + 2 * j);
                    float2 tv = *(const float2*)(Tr + 2 * j);
                    win[2 * j] = (v2f){pv.x, tv.x};
                    win[2 * j + 1] = (v2f){pv.y, tv.y};
                }
            } else {
#pragma unroll
                for (int j = 0; j < 16; ++j) {
                    bool ok = (gy < H) && (gxb + j < H);
                    win[j] = (v2f){ok ? Pr[j] : 0.f, ok ? Tr[j] : 0.f};
                }
            }
            v2f a01[6] = {}, a23[6] = {};
            float a4[6] = {};
#pragma unroll
            for (int xi = 0; xi < 16; ++xi) {
                v2f x01 = win[xi];
                v2f x23 = x01 * x01;      // v_pk_mul_f32
                float x4 = x01.x * x01.y;
#pragma unroll
                for (int o = 0; o < 6; ++o) {
                    int k = xi - o;
                    if (k >= 0 && k <= 10) {
                        float g = Gc[k];
                        a01[o] = a01[o] + g * x01;  // v_pk_fma_f32
                        a23[o] = a23[o] + g * x23;
                        a4[o] = fmaf(g, x4, a4[o]);
                    }
                }
            }
#pragma unroll
            for (int o = 0; o < 6; ++o) {
                int x = x0s + o;
                if (x < TX) {
                    int idx = r * HPITCH + x;
                    h01[idx] = a01[o];  // ds_write_b64
                    h23[idx] = a23[o];
                    h4s[idx] = a4[o];
                }
            }
        }
        __syncthreads();

        // ---- Stage 2: vertical conv + SSIM, packed, 3 outputs/thread ----
        {
            const int txl = tid & 31;
            const int y0 = (tid >> 5) * 3;  // 8 thread-rows x 3 = 24 outputs
            v2f m12[3] = {}, q12v[3] = {};
            float sA[3] = {};
#pragma unroll
            for (int yr = 0; yr < 13; ++yr) {  // 3 + 10 streamed rows
                int row = (y0 + yr) * HPITCH + txl;
                v2f v01 = h01[row];   // ds_read_b64
                v2f v23 = h23[row];
                float v4 = h4s[row];  // ds_read_b32
#pragma unroll
                for (int o = 0; o < 3; ++o) {
                    int k = yr - o;
                    if (k >= 0 && k <= 10) {
                        float gw = Gc[k];
                        m12[o] = m12[o] + gw * v01;
                        q12v[o] = q12v[o] + gw * v23;
                        sA[o] = fmaf(gw, v4, sA[o]);
                    }
                }
            }
            const float C1c = 1.0e-4f, C2c = 9.0e-4f;
            const int ox = oxp + s * TX + txl;
#pragma unroll
            for (int o = 0; o < 3; ++o) {
                if (ox < Hout && oy0 + y0 + o < Hout) {
                    float mu1 = m12[o].x, mu2 = m12[o].y;
                    float mu1s = mu1 * mu1, mu2s = mu2 * mu2, mu12 = mu1 * mu2;
                    float sig1 = q12v[o].x - mu1s;
                    float sig2 = q12v[o].y - mu2s;
                    float sig12 = sA[o] - mu12;
                    float v1 = 2.f * sig12 + C2c;
                    float v2 = sig1 + sig2 + C2c;
                    float den2 = mu1s + mu2s + C1c;
                    float num2 = 2.f * mu12 + C1c;
                    float inv = 1.f / (v2 * den2);  // one divide for both terms
                    cs_sum = fmaf(v1 * den2, inv, cs_sum);
                    sim_sum = fmaf(num2 * v1, inv, sim_sum);
                }
            }
        }
    }

    // ---- Block reduction (once per pair) ----
#pragma unroll
    for (int off = 32; off > 0; off >>= 1) {
        cs_sum += __shfl_down(cs_sum, off, 64);
        sim_sum += __shfl_down(sim_sum, off, 64);
    }
    int wave = tid >> 6;
    if ((tid & 63) == 0) {
        red[wave * 2 + 0] = sim_sum;
        red[wave * 2 + 1] = cs_sum;
    }
    __syncthreads();
    if (tid == 0) {
        float s = red[0] + red[2] + red[4] + red[6];
        float cc = red[1] + red[3] + red[5] + red[7];
        atomicAdd(&acc[(lvl * NCH + c) * 2 + 0], s);
        atomicAdd(&acc[(lvl * NCH + c) * 2 + 1], cc);
    }
}

__global__ void finalize_k(const float* __restrict__ acc, float* __restrict__ out) {
    if (threadIdx.x != 0) return;
    const double w[5] = {0.0448, 0.2856, 0.3001, 0.2363, 0.1333};
    const double counts[5] = {1014.0 * 1014.0, 502.0 * 502.0, 246.0 * 246.0,
                              118.0 * 118.0, 54.0 * 54.0};
    double total = 0.0;
    for (int c = 0; c < NCH; ++c) {
        double pc = 1.0;
        for (int l = 0; l < 4; ++l) {
            double mcs = (double)acc[(l * NCH + c) * 2 + 1] / counts[l];
            pc *= pow(mcs, w[l]);
        }
        double ms4 = (double)acc[(4 * NCH + c) * 2 + 0] / counts[4];
        double p2 = pow(ms4, w[4]);
        pc *= (p2 * p2) * (p2 * p2);  // pow2[-1] appears in all 4 product terms
        total += pc;
    }
    *out = (float)(1.0 - total);
}

extern "C" void kernel_launch(void* const* d_in, const int* in_sizes, int n_in,
                              void* d_out, int out_size, void* d_ws, size_t ws_size,
                              hipStream_t stream) {
    const float* P0 = (const float*)d_in[0];
    const float* T0 = (const float*)d_in[1];
    float* out = (float*)d_out;
    float* acc = (float*)d_ws;  // 100 used, 128 reserved

    const size_t n1 = (size_t)NCH * 512 * 512;
    const size_t n2 = (size_t)NCH * 256 * 256;
    const size_t n3 = (size_t)NCH * 128 * 128;
    const size_t n4 = (size_t)NCH * 64 * 64;
    float* p1 = acc + 128;
    float* t1 = p1 + n1;
    float* p2 = t1 + n1;
    float* t2 = p2 + n2;
    float* p3 = t2 + n2;
    float* t3 = p3 + n3;
    float* p4 = t3 + n3;
    float* t4 = p4 + n4;

    pool_all<<<2560, 256, 0, stream>>>(P0, T0, p1, t1, p2, t2, p3, t3, p4, t4, acc);

    Ptrs ptrs;
    ptrs.p[0] = P0; ptrs.t[0] = T0;
    ptrs.p[1] = p1; ptrs.t[1] = t1;
    ptrs.p[2] = p2; ptrs.t[2] = t2;
    ptrs.p[3] = p3; ptrs.t[3] = t3;
    ptrs.p[4] = p4; ptrs.t[4] = t4;

    ssim_all<<<dim3(BT, NCH, 1), 256, 0, stream>>>(ptrs, acc);

    finalize_k<<<1, 64, 0, stream>>>(acc, out);
}

// Round 8
// 236.764 us; speedup vs baseline: 1.7802x; 1.2920x over previous
//
#include <hip/hip_runtime.h>
#include <cstddef>

#define WIN 11
#define HALO 10
#define NCH 10

typedef float v2f __attribute__((ext_vector_type(2)));

// Normalized 1D Gaussian, sigma=1.5 (constexpr: unrolled taps fold to immediates)
constexpr float Gc[WIN] = {
    0.00102838f, 0.00759876f, 0.03600077f, 0.10936069f, 0.21300554f,
    0.26601173f, 0.21300554f, 0.10936069f, 0.03600077f, 0.00759876f,
    0.00102838f};

constexpr int HPITCH = 33;   // odd pitch: write banks spread, b64 reads 2-way (free)
constexpr int RS = 76;       // ring slots; per-iter window span = 74 <= 76 (disjoint)
constexpr int RSZ = RS * HPITCH;  // 2508 entries; LDS total 50.2 KB -> 3 blocks/CU

struct Ptrs {
    const float* p[5];
    const float* t[5];
};

// ---- One-shot pyramid: 64x64 level-0 tile -> levels 1..4, plus acc zeroing ----
__global__ __launch_bounds__(256) void pool_all(
    const float* __restrict__ P0, const float* __restrict__ T0,
    float* __restrict__ p1, float* __restrict__ t1,
    float* __restrict__ p2, float* __restrict__ t2,
    float* __restrict__ p3, float* __restrict__ t3,
    float* __restrict__ p4, float* __restrict__ t4,
    float* __restrict__ acc) {
    __shared__ float sp2[256], st2[256], sp3[64], st3[64];
    const int tid = threadIdx.x;
    if (blockIdx.x == 0 && tid < 128) acc[tid] = 0.f;

    const int b = blockIdx.x;  // 2560 = 10ch x 16 x 16
    const int bx = b & 15, by = (b >> 4) & 15, ch = b >> 8;
    const int tx = tid & 15, ty = tid >> 4;

    const size_t rbase =
        ((size_t)ch * 1024 + by * 64 + ty * 4) * 1024 + bx * 64 + tx * 4;
    float4 pr[4], tr[4];
#pragma unroll
    for (int r2 = 0; r2 < 4; ++r2) {
        pr[r2] = *(const float4*)(P0 + rbase + (size_t)r2 * 1024);
        tr[r2] = *(const float4*)(T0 + rbase + (size_t)r2 * 1024);
    }
    float p1a = 0.25f * ((pr[0].x + pr[0].y) + (pr[1].x + pr[1].y));
    float p1b = 0.25f * ((pr[0].z + pr[0].w) + (pr[1].z + pr[1].w));
    float p1c = 0.25f * ((pr[2].x + pr[2].y) + (pr[3].x + pr[3].y));
    float p1d = 0.25f * ((pr[2].z + pr[2].w) + (pr[3].z + pr[3].w));
    float t1a = 0.25f * ((tr[0].x + tr[0].y) + (tr[1].x + tr[1].y));
    float t1b = 0.25f * ((tr[0].z + tr[0].w) + (tr[1].z + tr[1].w));
    float t1c = 0.25f * ((tr[2].x + tr[2].y) + (tr[3].x + tr[3].y));
    float t1d = 0.25f * ((tr[2].z + tr[2].w) + (tr[3].z + tr[3].w));
    size_t o1 = ((size_t)ch * 512 + by * 32 + ty * 2) * 512 + bx * 32 + tx * 2;
    *(float2*)(p1 + o1) = make_float2(p1a, p1b);
    *(float2*)(p1 + o1 + 512) = make_float2(p1c, p1d);
    *(float2*)(t1 + o1) = make_float2(t1a, t1b);
    *(float2*)(t1 + o1 + 512) = make_float2(t1c, t1d);
    float p2v = 0.25f * ((p1a + p1b) + (p1c + p1d));
    float t2v = 0.25f * ((t1a + t1b) + (t1c + t1d));
    size_t o2 = ((size_t)ch * 256 + by * 16 + ty) * 256 + bx * 16 + tx;
    p2[o2] = p2v;
    t2[o2] = t2v;
    sp2[tid] = p2v;
    st2[tid] = t2v;
    __syncthreads();
    if (tid < 64) {
        int x3 = tid & 7, y3 = tid >> 3;
        int i0 = (2 * y3) * 16 + 2 * x3;
        float p3v = 0.25f * ((sp2[i0] + sp2[i0 + 1]) + (sp2[i0 + 16] + sp2[i0 + 17]));
        float t3v = 0.25f * ((st2[i0] + st2[i0 + 1]) + (st2[i0 + 16] + st2[i0 + 17]));
        size_t o3 = ((size_t)ch * 128 + by * 8 + y3) * 128 + bx * 8 + x3;
        p3[o3] = p3v;
        t3[o3] = t3v;
        sp3[tid] = p3v;
        st3[tid] = t3v;
    }
    __syncthreads();
    if (tid < 16) {
        int x4 = tid & 3, y4 = tid >> 2;
        int i0 = (2 * y4) * 8 + 2 * x4;
        float p4v = 0.25f * ((sp3[i0] + sp3[i0 + 1]) + (sp3[i0 + 8] + sp3[i0 + 9]));
        float t4v = 0.25f * ((sp3[i0] * 0.f + st3[i0] + st3[i0 + 1]) + (st3[i0 + 8] + st3[i0 + 9]));
        size_t o4 = ((size_t)ch * 64 + by * 4 + y4) * 64 + bx * 4 + x4;
        p4[o4] = p4v;
        t4[o4] = t4v;
    }
}

// Column-strip streaming SSIM: each block = 32-wide x <=256-tall output strip.
// 76-row LDS ring of h-rows; 32 output rows per iteration; ONE barrier/iter.
// Per-iter: S1 global loads issue first, S2 consumes resident ring rows
// (disjoint slots), S1 conv+write lands after -> load latency hides under S2.
// Per-channel blocks: lvl0 32x4=128, lvl1 16x2=32, lvl2 8, lvl3 4, lvl4 2 = 174.
__global__ __launch_bounds__(256) void ssim_strip(Ptrs ptrs,
                                                  float* __restrict__ acc) {
    __shared__ v2f h01[RSZ];    // (conv(p), conv(t))      20064 B
    __shared__ v2f h23[RSZ];    // (conv(p^2), conv(t^2))  20064 B
    __shared__ float h4s[RSZ];  // conv(p*t)               10032 B
    __shared__ float red[8];

    const int bxi = blockIdx.x;  // 0..173
    int lvl, base;
    if (bxi < 128)      { lvl = 0; base = 0; }
    else if (bxi < 160) { lvl = 1; base = 128; }
    else if (bxi < 168) { lvl = 2; base = 160; }
    else if (bxi < 172) { lvl = 3; base = 168; }
    else                { lvl = 4; base = 172; }
    const int local = bxi - base;
    const int H = 1024 >> lvl;
    const int Wout = H - HALO;               // == Hout
    const int ncol = 32 >> lvl;              // col strips: 32/16/8/4/2
    const int cs = local & (ncol - 1);
    const int rsi = local >> (5 - lvl);      // row strip: 4/2/1/1/1
    const int X0 = cs * 32;
    const int strip_y0 = rsi * 256;
    const int strip_rows = min(256, Wout - strip_y0);
    const int rows_needed = strip_rows + HALO;       // h-rows for this strip
    const int nIter = (strip_rows + 31) >> 5;

    const int c = blockIdx.y;
    const float* Pc = ptrs.p[lvl] + (size_t)c * H * H;
    const float* Tc = ptrs.t[lvl] + (size_t)c * H * H;
    const int tid = threadIdx.x;
    const int r6 = tid / 6;       // S1 row within batch
    const int seg = tid - r6 * 6;
    const int x0s = seg * 6;      // h-output cols x0s..x0s+5, inputs x0s..x0s+15
    const int gxb = X0 + x0s;

    // --- load one input row's 16-col window into registers ---
    auto load_row = [&](int gy, float2 lp[8], float2 lt[8]) {
        const float* Pr = Pc + (size_t)gy * H + gxb;
        const float* Tr = Tc + (size_t)gy * H + gxb;
        if (gxb + 16 <= H) {
#pragma unroll
            for (int j = 0; j < 8; ++j) {
                lp[j] = *(const float2*)(Pr + 2 * j);
                lt[j] = *(const float2*)(Tr + 2 * j);
            }
        } else {
#pragma unroll
            for (int j = 0; j < 8; ++j) {
                float2 a = make_float2(0.f, 0.f), b = make_float2(0.f, 0.f);
                if (gxb + 2 * j < H)     { a.x = Pr[2 * j];     b.x = Tr[2 * j]; }
                if (gxb + 2 * j + 1 < H) { a.y = Pr[2 * j + 1]; b.y = Tr[2 * j + 1]; }
                lp[j] = a;
                lt[j] = b;
            }
        }
    };

    // --- horizontal conv of one row -> ring slot (hrel % RS) ---
    auto conv_store = [&](int hrel, const float2 lp[8], const float2 lt[8]) {
        v2f a01[6] = {}, a23[6] = {};
        float a4[6] = {};
#pragma unroll
        for (int xi = 0; xi < 16; ++xi) {
            float pv = (xi & 1) ? lp[xi >> 1].y : lp[xi >> 1].x;
            float tv = (xi & 1) ? lt[xi >> 1].y : lt[xi >> 1].x;
            v2f x01 = (v2f){pv, tv};
            v2f x23 = x01 * x01;      // v_pk_mul_f32
            float x4 = pv * tv;
#pragma unroll
            for (int o = 0; o < 6; ++o) {
                int k = xi - o;
                if (k >= 0 && k <= 10) {
                    float g = Gc[k];
                    a01[o] = a01[o] + g * x01;  // v_pk_fma_f32
                    a23[o] = a23[o] + g * x23;
                    a4[o] = fmaf(g, x4, a4[o]);
                }
            }
        }
        const int sb = (hrel % RS) * HPITCH;
#pragma unroll
        for (int o = 0; o < 6; ++o) {
            int x = x0s + o;
            if (x < 32) {
                h01[sb + x] = a01[o];  // ds_write_b64
                h23[sb + x] = a23[o];
                h4s[sb + x] = a4[o];
            }
        }
    };

    // ---- Prologue: h-rows 0..41 (42 rows x 6 segs = 252 threads) ----
    if (tid < 252) {
        float2 lp[8], lt[8];
        load_row(strip_y0 + r6, lp, lt);
        conv_store(r6, lp, lt);
    }
    __syncthreads();

    // ---- Main loop: 32 output rows per iter, one barrier per iter ----
    float cs_sum = 0.f, sim_sum = 0.f;
    const int txl = tid & 31;
    const int g4 = (tid >> 5) * 4;
    int y0m = 0;  // (32*i) % RS
    for (int i = 0; i < nIter; ++i) {
        // S1 loads for NEXT window (rows 42+32i .. 73+32i), issued first
        float2 lp[8], lt[8];
        const int hrel = 42 + 32 * i + r6;
        const bool doS1 = (tid < 192) && (i + 1 < nIter) && (hrel < rows_needed);
        if (doS1) load_row(strip_y0 + hrel, lp, lt);

        // S2: vertical conv + SSIM from resident ring rows (independent of S1)
        {
            int s0 = y0m + g4;
            if (s0 >= RS) s0 -= RS;
            v2f m12[4] = {}, q12v[4] = {};
            float sA[4] = {};
#pragma unroll
            for (int yr = 0; yr < 14; ++yr) {
                int sl = s0 + yr;
                if (sl >= RS) sl -= RS;
                int row = sl * HPITCH + txl;
                v2f v01 = h01[row];   // ds_read_b64
                v2f v23 = h23[row];
                float v4 = h4s[row];  // ds_read_b32
#pragma unroll
                for (int o = 0; o < 4; ++o) {
                    int k = yr - o;
                    if (k >= 0 && k <= 10) {
                        float gw = Gc[k];
                        m12[o] = m12[o] + gw * v01;
                        q12v[o] = q12v[o] + gw * v23;
                        sA[o] = fmaf(gw, v4, sA[o]);
                    }
                }
            }
            const float C1c = 1.0e-4f, C2c = 9.0e-4f;
            const bool colok = (X0 + txl) < Wout;
#pragma unroll
            for (int o = 0; o < 4; ++o) {
                if (colok && (32 * i + g4 + o) < strip_rows) {
                    float mu1 = m12[o].x, mu2 = m12[o].y;
                    float mu1s = mu1 * mu1, mu2s = mu2 * mu2, mu12 = mu1 * mu2;
                    float sig1 = q12v[o].x - mu1s;
                    float sig2 = q12v[o].y - mu2s;
                    float sig12 = sA[o] - mu12;
                    float v1 = 2.f * sig12 + C2c;
                    float v2 = sig1 + sig2 + C2c;
                    float den2 = mu1s + mu2s + C1c;
                    float num2 = 2.f * mu12 + C1c;
                    float inv = 1.f / (v2 * den2);
                    cs_sum = fmaf(v1 * den2, inv, cs_sum);
                    sim_sum = fmaf(num2 * v1, inv, sim_sum);
                }
            }
        }

        // S1 conv + ring write (slots disjoint from S2's reads this iter)
        if (doS1) conv_store(hrel, lp, lt);

        y0m += 32;
        if (y0m >= RS) y0m -= RS;
        __syncthreads();
    }

    // ---- Block reduction ----
#pragma unroll
    for (int off = 32; off > 0; off >>= 1) {
        cs_sum += __shfl_down(cs_sum, off, 64);
        sim_sum += __shfl_down(sim_sum, off, 64);
    }
    int wave = tid >> 6;
    if ((tid & 63) == 0) {
        red[wave * 2 + 0] = sim_sum;
        red[wave * 2 + 1] = cs_sum;
    }
    __syncthreads();
    if (tid == 0) {
        float s = red[0] + red[2] + red[4] + red[6];
        float cc = red[1] + red[3] + red[5] + red[7];
        atomicAdd(&acc[(lvl * NCH + c) * 2 + 0], s);
        atomicAdd(&acc[(lvl * NCH + c) * 2 + 1], cc);
    }
}

__global__ void finalize_k(const float* __restrict__ acc, float* __restrict__ out) {
    if (threadIdx.x != 0) return;
    const double w[5] = {0.0448, 0.2856, 0.3001, 0.2363, 0.1333};
    const double counts[5] = {1014.0 * 1014.0, 502.0 * 502.0, 246.0 * 246.0,
                              118.0 * 118.0, 54.0 * 54.0};
    double total = 0.0;
    for (int c = 0; c < NCH; ++c) {
        double pc = 1.0;
        for (int l = 0; l < 4; ++l) {
            double mcs = (double)acc[(l * NCH + c) * 2 + 1] / counts[l];
            pc *= pow(mcs, w[l]);
        }
        double ms4 = (double)acc[(4 * NCH + c) * 2 + 0] / counts[4];
        double p2 = pow(ms4, w[4]);
        pc *= (p2 * p2) * (p2 * p2);  // pow2[-1] appears in all 4 product terms
        total += pc;
    }
    *out = (float)(1.0 - total);
}

extern "C" void kernel_launch(void* const* d_in, const int* in_sizes, int n_in,
                              void* d_out, int out_size, void* d_ws, size_t ws_size,
                              hipStream_t stream) {
    const float* P0 = (const float*)d_in[0];
    const float* T0 = (const float*)d_in[1];
    float* out = (float*)d_out;
    float* acc = (float*)d_ws;  // 100 used, 128 reserved

    const size_t n1 = (size_t)NCH * 512 * 512;
    const size_t n2 = (size_t)NCH * 256 * 256;
    const size_t n3 = (size_t)NCH * 128 * 128;
    const size_t n4 = (size_t)NCH * 64 * 64;
    float* p1 = acc + 128;
    float* t1 = p1 + n1;
    float* p2 = t1 + n1;
    float* t2 = p2 + n2;
    float* p3 = t2 + n2;
    float* t3 = p3 + n3;
    float* p4 = t3 + n3;
    float* t4 = p4 + n4;

    pool_all<<<2560, 256, 0, stream>>>(P0, T0, p1, t1, p2, t2, p3, t3, p4, t4, acc);

    Ptrs ptrs;
    ptrs.p[0] = P0; ptrs.t[0] = T0;
    ptrs.p[1] = p1; ptrs.t[1] = t1;
    ptrs.p[2] = p2; ptrs.t[2] = t2;
    ptrs.p[3] = p3; ptrs.t[3] = t3;
    ptrs.p[4] = p4; ptrs.t[4] = t4;

    ssim_strip<<<dim3(174, NCH, 1), 256, 0, stream>>>(ptrs, acc);

    finalize_k<<<1, 64, 0, stream>>>(acc, out);
}